// Round 1
// baseline (291.351 us; speedup 1.0000x reference)
//
#include <hip/hip_runtime.h>

// IDMForwardSim: act_seq/att_scores for B=262144 rows, T=40 steps.
// Fusion insight: logits = x @ (W1@W2) + (b1@W2 + b2)  (no nonlinearity
// between the two matmuls) -> precompute Wc (128x40) + bc (40) in d_ws.

#define TT 40
#define DD 128
#define HH 100
#define ACT_CLIP 3.5f
#define ATT_TEMP 5.0f

__global__ __launch_bounds__(256) void precompute_wc(
    const float* __restrict__ W1, const float* __restrict__ b1,
    const float* __restrict__ W2, const float* __restrict__ b2,
    float* __restrict__ wc, float* __restrict__ bc)
{
    int idx = blockIdx.x * 256 + threadIdx.x;
    if (idx < DD * TT) {
        int d = idx / TT, t = idx % TT;
        float acc = 0.0f;
        for (int k = 0; k < HH; ++k)
            acc = fmaf(W1[d * HH + k], W2[k * TT + t], acc);
        wc[idx] = acc;
    } else if (idx < DD * TT + TT) {
        int t = idx - DD * TT;
        float acc = b2[t];
        for (int k = 0; k < HH; ++k)
            acc = fmaf(b1[k], W2[k * TT + t], acc);
        bc[t] = acc;
    }
}

__global__ __launch_bounds__(256) void idm_fused(
    const float* __restrict__ us,   // (B, T, 7)
    const float* __restrict__ prm,  // (B, 5)
    const float* __restrict__ x,    // (B, 128)
    const float* __restrict__ wc,   // (128, 40) = W1@W2
    const float* __restrict__ bc,   // (40) = b1@W2 + b2
    float* __restrict__ out,        // act (B*T) then att (B*T)
    int B)
{
    int row = blockIdx.x * 256 + threadIdx.x;
    if (row >= B) return;

    // ---- logits = x_row @ Wc + bc ------------------------------------
    float acc[TT];
#pragma unroll
    for (int t = 0; t < TT; ++t) acc[t] = bc[t];   // uniform -> s_load

    const float* xr = x + (size_t)row * DD;
    // k-loop kept rolled (32 iters); wc addr is wave-uniform -> s_load,
    // x loads are per-lane contiguous float4 streaming.
    for (int k = 0; k < DD; k += 4) {
        float4 xv = *reinterpret_cast<const float4*>(xr + k);
        float xs[4] = {xv.x, xv.y, xv.z, xv.w};
#pragma unroll
        for (int kk = 0; kk < 4; ++kk) {
#pragma unroll
            for (int t = 0; t < TT; ++t)
                acc[t] = fmaf(xs[kk], wc[(k + kk) * TT + t], acc[t]);
        }
    }

    // ---- att = sigmoid(5 * logits)  (overwrite acc in-place) ---------
#pragma unroll
    for (int t = 0; t < TT; ++t)
        acc[t] = __builtin_amdgcn_rcpf(1.0f + __expf(-ATT_TEMP * acc[t]));

    // ---- per-row IDM params ------------------------------------------
    const float* pr = prm + (size_t)row * 5;
    float desired_v   = pr[0];
    float desired_tgap = pr[1];
    float min_jamx    = pr[2];
    float max_act     = pr[3];
    float min_act     = pr[4];
    float inv_dv = __builtin_amdgcn_rcpf(desired_v);
    float coef   = 0.5f / sqrtf(max_act * min_act);   // 1/(2*sqrt(ma*mi))

    // ---- stream s rows in 4-timestep groups (7 float4 each) ----------
    const float* srow = us + (size_t)row * (TT * 7);
    float* oact = out + (size_t)row * TT;
    float* oatt = out + (size_t)B * TT + (size_t)row * TT;

#pragma unroll
    for (int g = 0; g < TT / 4; ++g) {
        float f[28];
#pragma unroll
        for (int q = 0; q < 7; ++q) {
            float4 v = *reinterpret_cast<const float4*>(srow + g * 28 + q * 4);
            f[q * 4 + 0] = v.x; f[q * 4 + 1] = v.y;
            f[q * 4 + 2] = v.z; f[q * 4 + 3] = v.w;
        }
        float ares[4], tres[4];
#pragma unroll
        for (int tt = 0; tt < 4; ++tt) {
            float vel = f[tt * 7 + 0];
            float dvl = f[tt * 7 + 2], dxl = f[tt * 7 + 3];
            float dvm = f[tt * 7 + 5], dxm = f[tt * 7 + 6];

            float r  = vel * inv_dv;
            float r2 = r * r;
            float common = 1.0f - r2 * r2;                 // 1 - (v/v0)^4
            float base = fmaf(desired_tgap, vel, min_jamx);
            float gl = fmaf(vel * dvl, coef, base);        // desired_gap fl
            float gm = fmaf(vel * dvm, coef, base);        // desired_gap fm
            float ql = gl * __builtin_amdgcn_rcpf(dxl);
            float qm = gm * __builtin_amdgcn_rcpf(dxm);
            float al = max_act * (common - ql * ql);
            float am = max_act * (common - qm * qm);
            al = fminf(fmaxf(al, -ACT_CLIP), ACT_CLIP);
            am = fminf(fmaxf(am, -ACT_CLIP), ACT_CLIP);
            float a = acc[g * 4 + tt];
            ares[tt] = fmaf(a, al - am, am);               // a*fl + (1-a)*fm
            tres[tt] = a;
        }
        *reinterpret_cast<float4*>(oact + g * 4) =
            make_float4(ares[0], ares[1], ares[2], ares[3]);
        *reinterpret_cast<float4*>(oatt + g * 4) =
            make_float4(tres[0], tres[1], tres[2], tres[3]);
    }
}

extern "C" void kernel_launch(void* const* d_in, const int* in_sizes, int n_in,
                              void* d_out, int out_size, void* d_ws, size_t ws_size,
                              hipStream_t stream) {
    const float* us  = (const float*)d_in[0];  // unscaled_s (B,T,7)
    const float* prm = (const float*)d_in[1];  // idm_param (B,5)
    const float* x   = (const float*)d_in[2];  // decoder_output (B,128)
    const float* W1  = (const float*)d_in[3];  // (128,100)
    const float* b1  = (const float*)d_in[4];  // (100,)
    const float* W2  = (const float*)d_in[5];  // (100,40)
    const float* b2  = (const float*)d_in[6];  // (40,)
    float* out = (float*)d_out;

    int B = in_sizes[1] / 5;

    float* wc = (float*)d_ws;           // 128*40 floats = 20480 B
    float* bc = wc + DD * TT;           // 40 floats

    int pre_items = DD * TT + TT;       // 5160
    hipLaunchKernelGGL(precompute_wc, dim3((pre_items + 255) / 256), dim3(256),
                       0, stream, W1, b1, W2, b2, wc, bc);
    hipLaunchKernelGGL(idm_fused, dim3((B + 255) / 256), dim3(256),
                       0, stream, us, prm, x, wc, bc, out, B);
}

// Round 2
// 287.872 us; speedup vs baseline: 1.0121x; 1.0121x over previous
//
#include <hip/hip_runtime.h>

// IDMForwardSim: act_seq/att_scores for B=262144 rows, T=40 steps.
// logits = x @ (W1@W2) + (b1@W2 + b2)  (no nonlinearity between matmuls)
// -> precompute Wc (128x40) + bc (40) into d_ws, stage in LDS per block.

#define TT 40
#define DD 128
#define HH 100
#define ACT_CLIP 3.5f
#define ATT_TEMP 5.0f

__global__ __launch_bounds__(256) void precompute_wc(
    const float* __restrict__ W1, const float* __restrict__ b1,
    const float* __restrict__ W2, const float* __restrict__ b2,
    float* __restrict__ wc, float* __restrict__ bc)
{
    int idx = blockIdx.x * 256 + threadIdx.x;
    if (idx < DD * TT) {
        int d = idx / TT, t = idx % TT;
        float acc = 0.0f;
        for (int k = 0; k < HH; ++k)
            acc = fmaf(W1[d * HH + k], W2[k * TT + t], acc);
        wc[idx] = acc;
    } else if (idx < DD * TT + TT) {
        int t = idx - DD * TT;
        float acc = b2[t];
        for (int k = 0; k < HH; ++k)
            acc = fmaf(b1[k], W2[k * TT + t], acc);
        bc[t] = acc;
    }
}

// 256 threads/block, 1 row/thread. Grid = B/256 = 1024 blocks = 4 blocks/CU
// -> 16 waves/CU cap, so ask for 4 waves/EU -> ~128 VGPR budget.
__global__ __launch_bounds__(256, 4) void idm_fused(
    const float* __restrict__ us,   // (B, T, 7)
    const float* __restrict__ prm,  // (B, 5)
    const float* __restrict__ x,    // (B, 128)
    const float* __restrict__ wc,   // (128, 40) = W1@W2
    const float* __restrict__ bc,   // (40) = b1@W2 + b2
    float* __restrict__ out,        // act (B*T) then att (B*T)
    int B)
{
    __shared__ float swc[DD * TT];  // 20480 B
    __shared__ float sbc[TT];

    int tid = threadIdx.x;
    for (int i = tid; i < DD * TT; i += 256) swc[i] = wc[i];
    if (tid < TT) sbc[tid] = bc[tid];
    __syncthreads();

    int row = blockIdx.x * 256 + tid;
    if (row >= B) return;

    // ---- hoist per-row IDM params (in flight during matvec) ----------
    const float* pr = prm + (size_t)row * 5;
    float desired_v    = pr[0];
    float desired_tgap = pr[1];
    float min_jamx     = pr[2];
    float max_act      = pr[3];
    float min_act      = pr[4];

    // ---- logits = x_row @ Wc + bc ------------------------------------
    float acc[TT];
#pragma unroll
    for (int tq = 0; tq < TT / 4; ++tq) {
        float4 b = *reinterpret_cast<const float4*>(&sbc[tq * 4]);
        acc[tq * 4 + 0] = b.x; acc[tq * 4 + 1] = b.y;
        acc[tq * 4 + 2] = b.z; acc[tq * 4 + 3] = b.w;
    }

    const float* xr = x + (size_t)row * DD;
    for (int k = 0; k < DD; k += 8) {
        float4 xv0 = *reinterpret_cast<const float4*>(xr + k);
        float4 xv1 = *reinterpret_cast<const float4*>(xr + k + 4);
        float xs[8] = {xv0.x, xv0.y, xv0.z, xv0.w,
                       xv1.x, xv1.y, xv1.z, xv1.w};
#pragma unroll
        for (int kk = 0; kk < 8; ++kk) {
            const float4* wrow =
                reinterpret_cast<const float4*>(&swc[(k + kk) * TT]);
#pragma unroll
            for (int tq = 0; tq < TT / 4; ++tq) {
                float4 w = wrow[tq];            // ds_read_b128 broadcast
                acc[tq * 4 + 0] = fmaf(xs[kk], w.x, acc[tq * 4 + 0]);
                acc[tq * 4 + 1] = fmaf(xs[kk], w.y, acc[tq * 4 + 1]);
                acc[tq * 4 + 2] = fmaf(xs[kk], w.z, acc[tq * 4 + 2]);
                acc[tq * 4 + 3] = fmaf(xs[kk], w.w, acc[tq * 4 + 3]);
            }
        }
    }

    // ---- att = sigmoid(5 * logits)  (overwrite acc in-place) ---------
#pragma unroll
    for (int t = 0; t < TT; ++t)
        acc[t] = __builtin_amdgcn_rcpf(1.0f + __expf(-ATT_TEMP * acc[t]));

    float inv_dv = __builtin_amdgcn_rcpf(desired_v);
    float coef   = 0.5f / sqrtf(max_act * min_act);   // 1/(2*sqrt(ma*mi))

    // ---- stream s rows in 4-timestep groups (7 float4 each) ----------
    const float* srow = us + (size_t)row * (TT * 7);
    float* oact = out + (size_t)row * TT;
    float* oatt = out + (size_t)B * TT + (size_t)row * TT;

#pragma unroll
    for (int g = 0; g < TT / 4; ++g) {
        float f[28];
#pragma unroll
        for (int q = 0; q < 7; ++q) {
            float4 v = *reinterpret_cast<const float4*>(srow + g * 28 + q * 4);
            f[q * 4 + 0] = v.x; f[q * 4 + 1] = v.y;
            f[q * 4 + 2] = v.z; f[q * 4 + 3] = v.w;
        }
        float ares[4], tres[4];
#pragma unroll
        for (int tt = 0; tt < 4; ++tt) {
            float vel = f[tt * 7 + 0];
            float dvl = f[tt * 7 + 2], dxl = f[tt * 7 + 3];
            float dvm = f[tt * 7 + 5], dxm = f[tt * 7 + 6];

            float r  = vel * inv_dv;
            float r2 = r * r;
            float common = 1.0f - r2 * r2;                 // 1 - (v/v0)^4
            float base = fmaf(desired_tgap, vel, min_jamx);
            float gl = fmaf(vel * dvl, coef, base);        // desired_gap fl
            float gm = fmaf(vel * dvm, coef, base);        // desired_gap fm
            float ql = gl * __builtin_amdgcn_rcpf(dxl);
            float qm = gm * __builtin_amdgcn_rcpf(dxm);
            float al = max_act * (common - ql * ql);
            float am = max_act * (common - qm * qm);
            al = fminf(fmaxf(al, -ACT_CLIP), ACT_CLIP);
            am = fminf(fmaxf(am, -ACT_CLIP), ACT_CLIP);
            float a = acc[g * 4 + tt];
            ares[tt] = fmaf(a, al - am, am);               // a*fl + (1-a)*fm
            tres[tt] = a;
        }
        *reinterpret_cast<float4*>(oact + g * 4) =
            make_float4(ares[0], ares[1], ares[2], ares[3]);
        *reinterpret_cast<float4*>(oatt + g * 4) =
            make_float4(tres[0], tres[1], tres[2], tres[3]);
    }
}

extern "C" void kernel_launch(void* const* d_in, const int* in_sizes, int n_in,
                              void* d_out, int out_size, void* d_ws, size_t ws_size,
                              hipStream_t stream) {
    const float* us  = (const float*)d_in[0];  // unscaled_s (B,T,7)
    const float* prm = (const float*)d_in[1];  // idm_param (B,5)
    const float* x   = (const float*)d_in[2];  // decoder_output (B,128)
    const float* W1  = (const float*)d_in[3];  // (128,100)
    const float* b1  = (const float*)d_in[4];  // (100,)
    const float* W2  = (const float*)d_in[5];  // (100,40)
    const float* b2  = (const float*)d_in[6];  // (40,)
    float* out = (float*)d_out;

    int B = in_sizes[1] / 5;

    float* wc = (float*)d_ws;           // 128*40 floats = 20480 B
    float* bc = wc + DD * TT;           // 40 floats

    int pre_items = DD * TT + TT;       // 5160
    hipLaunchKernelGGL(precompute_wc, dim3((pre_items + 255) / 256), dim3(256),
                       0, stream, W1, b1, W2, b2, wc, bc);
    hipLaunchKernelGGL(idm_fused, dim3((B + 255) / 256), dim3(256),
                       0, stream, us, prm, x, wc, bc, out, B);
}

// Round 3
// 133.011 us; speedup vs baseline: 2.1904x; 2.1643x over previous
//
#include <hip/hip_runtime.h>

// IDMForwardSim, 3-kernel structure:
//  1) precompute_pack: Wc = W1@W2 packed as bf16 hi/lo MFMA B-fragments (ws)
//  2) matvec_att: att = sigmoid(5*(x@Wc+bc)) via 16x16x32 bf16 MFMA (split),
//     written straight to the att half of d_out
//  3) epilogue_k: IDM math, LDS-staged coalesced streaming of us/att

#define TT 40
#define DD 128
#define ACT_CLIP 3.5f
#define ATT_TEMP 5.0f

typedef short short8 __attribute__((ext_vector_type(8)));
typedef float f32x4 __attribute__((ext_vector_type(4)));

__device__ __forceinline__ unsigned int bf16_rne(float v) {
    unsigned int u = __float_as_uint(v);
    return (u + 0x7FFFu + ((u >> 16) & 1u)) >> 16;
}

// ---------------------------------------------------------------------------
// Kernel 1: pack Wc (128x48, zero-padded cols 40..47) as MFMA B-fragments.
// Record (s,n,h): s=k-step(0..3), n=n-tile(0..2), h=0 hi/1 lo. 64 lanes x 16B.
// Element j of lane l: k = s*32 + (l>>4)*8 + j ; col = n*16 + (l&15).
// ---------------------------------------------------------------------------
__global__ __launch_bounds__(256) void precompute_pack(
    const float* __restrict__ W1, const float* __restrict__ b1,
    const float* __restrict__ W2, const float* __restrict__ b2,
    unsigned int* __restrict__ wpack,   // 1536 * 16B records
    float* __restrict__ bcp)            // 48 floats
{
    int idx = blockIdx.x * 256 + threadIdx.x;
    if (idx < 1536) {
        int l   = idx & 63;
        int rec = idx >> 6;           // ((s*3+n)*2+h)
        int h   = rec & 1;
        int sn  = rec >> 1;           // s*3+n
        int n   = sn % 3, s = sn / 3;
        int col = n * 16 + (l & 15);
        int k0  = s * 32 + (l >> 4) * 8;
        unsigned short hv[8];
#pragma unroll
        for (int j = 0; j < 8; ++j) {
            float v = 0.0f;
            if (col < TT) {
                int k = k0 + j;
                for (int m = 0; m < 100; ++m)
                    v = fmaf(W1[k * 100 + m], W2[m * TT + col], v);
            }
            unsigned int hi = bf16_rne(v);
            float hif = __uint_as_float(hi << 16);
            unsigned int lo = bf16_rne(v - hif);
            hv[j] = (unsigned short)(h == 0 ? hi : lo);
        }
        uint4 o;
        o.x = hv[0] | ((unsigned)hv[1] << 16);
        o.y = hv[2] | ((unsigned)hv[3] << 16);
        o.z = hv[4] | ((unsigned)hv[5] << 16);
        o.w = hv[6] | ((unsigned)hv[7] << 16);
        reinterpret_cast<uint4*>(wpack)[idx] = o;
    } else if (idx < 1536 + 48) {
        int t = idx - 1536;
        float v = 0.0f;
        if (t < TT) {
            v = b2[t];
            for (int m = 0; m < 100; ++m)
                v = fmaf(b1[m], W2[m * TT + t], v);
        }
        bcp[t] = v;
    }
}

// ---------------------------------------------------------------------------
// Kernel 2: att = sigmoid(5*(x@Wc+bc)). Block 256 = 4 waves, 64 rows/block.
// Wave w: rows w*16..w*16+15. 3 n-tiles x 4 k-steps x 3 split-MFMAs.
// ---------------------------------------------------------------------------
__global__ __launch_bounds__(256, 4) void matvec_att(
    const float* __restrict__ x,
    const unsigned int* __restrict__ wpack,
    const float* __restrict__ bcp,
    float* __restrict__ attout)          // = d_out + B*TT
{
    __shared__ unsigned int swp[6144];   // 24576 B
    __shared__ float sbc[48];
    __shared__ float satt[64 * TT];      // 10240 B

    int tid = threadIdx.x;
    {
        const uint4* src = reinterpret_cast<const uint4*>(wpack);
        uint4* dst = reinterpret_cast<uint4*>(swp);
#pragma unroll
        for (int i = 0; i < 6; ++i) dst[tid + 256 * i] = src[tid + 256 * i];
        if (tid < 48) sbc[tid] = bcp[tid];
    }
    __syncthreads();

    int wave = tid >> 6, lane = tid & 63;
    int l15 = lane & 15, lk = lane >> 4;
    size_t row0 = (size_t)blockIdx.x * 64 + wave * 16 + l15;  // A-row of lane
    const float* xr = x + row0 * DD;

    float4 xv[8];
#pragma unroll
    for (int s = 0; s < 4; ++s) {
        xv[2 * s]     = *reinterpret_cast<const float4*>(xr + s * 32 + lk * 8);
        xv[2 * s + 1] = *reinterpret_cast<const float4*>(xr + s * 32 + lk * 8 + 4);
    }

    f32x4 acc[3] = {f32x4{0,0,0,0}, f32x4{0,0,0,0}, f32x4{0,0,0,0}};

#pragma unroll
    for (int s = 0; s < 4; ++s) {
        float fs[8] = {xv[2*s].x, xv[2*s].y, xv[2*s].z, xv[2*s].w,
                       xv[2*s+1].x, xv[2*s+1].y, xv[2*s+1].z, xv[2*s+1].w};
        union { unsigned int u[4]; short8 v; } ah, al;
#pragma unroll
        for (int p = 0; p < 4; ++p) {
            unsigned int h0 = bf16_rne(fs[2*p]);
            unsigned int h1 = bf16_rne(fs[2*p+1]);
            float f0 = __uint_as_float(h0 << 16);
            float f1 = __uint_as_float(h1 << 16);
            unsigned int l0 = bf16_rne(fs[2*p] - f0);
            unsigned int l1 = bf16_rne(fs[2*p+1] - f1);
            ah.u[p] = h0 | (h1 << 16);
            al.u[p] = l0 | (l1 << 16);
        }
#pragma unroll
        for (int n = 0; n < 3; ++n) {
            int base = (s * 3 + n) * 512;   // uints: 2 records x 256 uints
            short8 bh = *reinterpret_cast<const short8*>(&swp[base + lane * 4]);
            short8 bl = *reinterpret_cast<const short8*>(&swp[base + 256 + lane * 4]);
            acc[n] = __builtin_amdgcn_mfma_f32_16x16x32_bf16(ah.v, bh, acc[n], 0, 0, 0);
            acc[n] = __builtin_amdgcn_mfma_f32_16x16x32_bf16(al.v, bh, acc[n], 0, 0, 0);
            acc[n] = __builtin_amdgcn_mfma_f32_16x16x32_bf16(ah.v, bl, acc[n], 0, 0, 0);
        }
    }

    // C/D: col = lane&15 (+16*n), row = wave*16 + (lane>>4)*4 + reg
#pragma unroll
    for (int n = 0; n < 3; ++n) {
        int col = n * 16 + l15;
        if (col < TT) {
            float bias = sbc[col];
#pragma unroll
            for (int r = 0; r < 4; ++r) {
                int rowl = wave * 16 + lk * 4 + r;
                float L = acc[n][r] + bias;
                satt[rowl * TT + col] =
                    __builtin_amdgcn_rcpf(1.0f + __expf(-ATT_TEMP * L));
            }
        }
    }
    __syncthreads();

    float4* dst = reinterpret_cast<float4*>(attout + (size_t)blockIdx.x * 64 * TT);
    const float4* s4 = reinterpret_cast<const float4*>(satt);
    for (int i = tid; i < 640; i += 256) dst[i] = s4[i];
}

// ---------------------------------------------------------------------------
// Kernel 3: IDM epilogue. Block 320 = 5 waves, 32 rows/block.
// Stage us (35840B) + att (5120B) via coalesced float4 -> LDS, then each
// thread = (row, 4-timestep group).
// ---------------------------------------------------------------------------
__global__ __launch_bounds__(320) void epilogue_k(
    const float* __restrict__ us, const float* __restrict__ prm,
    const float* __restrict__ attg,   // = d_out + B*TT (sigmoided by k2)
    float* __restrict__ act)          // = d_out
{
    __shared__ float sus[32 * 280];   // 35840 B
    __shared__ float sat[32 * TT];    // 5120 B

    int tid = threadIdx.x;
    size_t blk = blockIdx.x;
    {
        const float4* su = reinterpret_cast<const float4*>(us + blk * 32 * 280);
        float4* du = reinterpret_cast<float4*>(sus);
#pragma unroll
        for (int i = 0; i < 7; ++i) du[tid + 320 * i] = su[tid + 320 * i];
        reinterpret_cast<float4*>(sat)[tid] =
            reinterpret_cast<const float4*>(attg + blk * 32 * TT)[tid];
    }
    __syncthreads();

    int row = tid / 10;
    int tg  = tid - row * 10;
    size_t row_g = blk * 32 + row;

    const float* pr = prm + row_g * 5;
    float desired_v    = pr[0];
    float desired_tgap = pr[1];
    float min_jamx     = pr[2];
    float max_act      = pr[3];
    float min_act      = pr[4];
    float inv_dv = __builtin_amdgcn_rcpf(desired_v);
    float coef   = 0.5f / sqrtf(max_act * min_act);

    float f[28];
    const float4* fv = reinterpret_cast<const float4*>(sus + row * 280 + tg * 28);
#pragma unroll
    for (int q = 0; q < 7; ++q) {
        float4 v = fv[q];
        f[q * 4 + 0] = v.x; f[q * 4 + 1] = v.y;
        f[q * 4 + 2] = v.z; f[q * 4 + 3] = v.w;
    }
    float4 a4 = *reinterpret_cast<const float4*>(sat + row * TT + tg * 4);
    float av[4] = {a4.x, a4.y, a4.z, a4.w};

    float ares[4];
#pragma unroll
    for (int tt = 0; tt < 4; ++tt) {
        float vel = f[tt * 7 + 0];
        float dvl = f[tt * 7 + 2], dxl = f[tt * 7 + 3];
        float dvm = f[tt * 7 + 5], dxm = f[tt * 7 + 6];

        float r  = vel * inv_dv;
        float r2 = r * r;
        float common = 1.0f - r2 * r2;
        float base = fmaf(desired_tgap, vel, min_jamx);
        float gl = fmaf(vel * dvl, coef, base);
        float gm = fmaf(vel * dvm, coef, base);
        float ql = gl * __builtin_amdgcn_rcpf(dxl);
        float qm = gm * __builtin_amdgcn_rcpf(dxm);
        float al = max_act * (common - ql * ql);
        float am = max_act * (common - qm * qm);
        al = fminf(fmaxf(al, -ACT_CLIP), ACT_CLIP);
        am = fminf(fmaxf(am, -ACT_CLIP), ACT_CLIP);
        ares[tt] = fmaf(av[tt], al - am, am);
    }
    *reinterpret_cast<float4*>(act + row_g * TT + tg * 4) =
        make_float4(ares[0], ares[1], ares[2], ares[3]);
}

extern "C" void kernel_launch(void* const* d_in, const int* in_sizes, int n_in,
                              void* d_out, int out_size, void* d_ws, size_t ws_size,
                              hipStream_t stream) {
    const float* us  = (const float*)d_in[0];
    const float* prm = (const float*)d_in[1];
    const float* x   = (const float*)d_in[2];
    const float* W1  = (const float*)d_in[3];
    const float* b1  = (const float*)d_in[4];
    const float* W2  = (const float*)d_in[5];
    const float* b2  = (const float*)d_in[6];
    float* out = (float*)d_out;

    int B = in_sizes[1] / 5;                 // 262144

    unsigned int* wpack = (unsigned int*)d_ws;          // 24576 B
    float* bcp = (float*)((char*)d_ws + 24576);         // 192 B

    float* attout = out + (size_t)B * TT;    // att half of d_out (final!)

    hipLaunchKernelGGL(precompute_pack, dim3(7), dim3(256), 0, stream,
                       W1, b1, W2, b2, wpack, bcp);
    hipLaunchKernelGGL(matvec_att, dim3(B / 64), dim3(256), 0, stream,
                       x, wpack, bcp, attout);
    hipLaunchKernelGGL(epilogue_k, dim3(B / 32), dim3(320), 0, stream,
                       us, prm, attout, out);
}